// Round 9
// baseline (4695.279 us; speedup 1.0000x reference)
//
#include <hip/hip_runtime.h>

#define CPG 8
#define NGRP 32
#define NB 16
#define HW 3136
#define HU 784       // float4 units per channel image
#define N2 36
#define N3 120

typedef float vfloat4 __attribute__((ext_vector_type(4)));

__host__ __device__ constexpr int idx2(int i, int j) {
    return i * CPG - i * (i - 1) / 2 + (j - i);
}
__host__ __device__ constexpr int idx3(int a, int b, int c) {
    int base = 0;
    for (int t = 0; t < a; ++t) { int m = CPG - t; base += m * (m + 1) / 2; }
    for (int t = a; t < b; ++t) base += CPG - t;
    return base + (c - b);
}

__device__ inline vfloat4 splat4(float s) { return (vfloat4){s, s, s, s}; }

// One wave-uniform ds_read_b128 per feature (16B = this wave's 4 outputs),
// feeding 8 vfloat4 fmacs (2 pixel-quads x 4 outputs). DS instrs per unit of
// work HALVED vs the 8-output layout; that pipe was ~50% loaded and serialized
// against VALU (R3/R8 accounting: 94k VALU + 84k LDS ~= 163k measured cycles).
#define ACCUM(F, TLO, THI) do {                                                \
    const vfloat4 w = *reinterpret_cast<const vfloat4*>(wrow + (F) * 8);       \
    acc0[0] += w.x * (TLO); acc1[0] += w.x * (THI);                            \
    acc0[1] += w.y * (TLO); acc1[1] += w.y * (THI);                            \
    acc0[2] += w.z * (TLO); acc1[2] += w.z * (THI);                            \
    acc0[3] += w.w * (TLO); acc1[3] += w.w * (THI);                            \
} while (0)

// scheduler fence: prevents mass ds_read hoisting -> bounded register pressure
#define FENCE() __builtin_amdgcn_sched_barrier(0)

__global__ __launch_bounds__(256, 4) void hoaf_kernel(
    const float* __restrict__ x,
    const float* __restrict__ w1, const float* __restrict__ b1,
    const float* __restrict__ w2, const float* __restrict__ b2,
    const float* __restrict__ w3, const float* __restrict__ b3,
    float* __restrict__ out)
{
    // wt[f][o]: f 0-7 deg1, 8-43 deg2, 44-163 deg3, 164 = summed bias
    __shared__ __align__(16) float wt[165][8];

    const int tid   = threadIdx.x;
    const int g     = blockIdx.x;   // block-uniform group
    const int b     = blockIdx.y;
    const int chunk = blockIdx.z;   // 0..3; chunk 3 is a runt (16 quads)

    for (int idx = tid; idx < 165 * 8; idx += 256) {
        const int f = idx >> 3, o = idx & 7;
        const int ch = g * CPG + o;
        float v;
        if (f < 8)        v = w1[ch * CPG + f];
        else if (f < 44)  v = w2[ch * N2 + (f - 8)];
        else if (f < 164) v = w3[ch * N3 + (f - 44)];
        else              v = b1[ch] + b2[ch] + b3[ch];
        wt[f][o] = v;
    }
    __syncthreads();

    // wave -> (output-half, quad-set); lane -> 2 pixel-quads (8 pixels)
    const int wave = tid >> 6;
    const int lane = tid & 63;
    const int half = wave & 1;    // 0: outputs 0-3, 1: outputs 4-7
    const int qset = wave >> 1;   // 0,1

    const int q0 = chunk * 256 + qset * 128 + lane;
    const int q1 = q0 + 64;
    if (q0 >= HU) return;
    const bool has1 = (q1 < HU);
    const int  q1c  = has1 ? q1 : q0;   // clamped for loads

    const float* wrow = &wt[0][0] + half * 4;   // wave-uniform weight base

    const size_t base = ((size_t)(b * NGRP + g) * CPG) * HW;
    const vfloat4* x4 = (const vfloat4*)(x + base);
    vfloat4*       o4 = (vfloat4*)(out + base);

    vfloat4 xlo[CPG], xhi[CPG];
#pragma unroll
    for (int c = 0; c < CPG; ++c) {
        xlo[c] = x4[(size_t)c * HU + q0];
        xhi[c] = x4[(size_t)c * HU + q1c];
    }

    vfloat4 acc0[4], acc1[4];
#pragma unroll
    for (int o = 0; o < 4; ++o) {
        acc0[o] = splat4(wt[164][half * 4 + o]);
        acc1[o] = acc0[o];
    }

    // degree 1, fenced every 2 features
#pragma unroll
    for (int k = 0; k < CPG; k += 2) {
        ACCUM(k, xlo[k], xhi[k]);
        ACCUM(k + 1, xlo[k + 1], xhi[k + 1]);
        FENCE();
    }

    // degree 2 & 3: pair product (i<=j) feeds triples (a<=i<=j);
    // one fence per (i,j) group bounds in-flight weight reads
#pragma unroll
    for (int i = 0; i < CPG; ++i) {
#pragma unroll
        for (int j = i; j < CPG; ++j) {
            const vfloat4 plo = xlo[i] * xlo[j];
            const vfloat4 phi = xhi[i] * xhi[j];
            ACCUM(8 + idx2(i, j), plo, phi);
#pragma unroll
            for (int a = 0; a <= i; ++a) {
                const vfloat4 tlo = xlo[a] * plo;
                const vfloat4 thi = xhi[a] * phi;
                ACCUM(44 + idx3(a, i, j), tlo, thi);
            }
            FENCE();
        }
    }

#pragma unroll
    for (int o = 0; o < 4; ++o) {
        const size_t row = (size_t)(half * 4 + o) * HU;
        o4[row + q0] = acc0[o];
        if (has1) o4[row + q1] = acc1[o];
    }
}

extern "C" void kernel_launch(void* const* d_in, const int* in_sizes, int n_in,
                              void* d_out, int out_size, void* d_ws, size_t ws_size,
                              hipStream_t stream) {
    const float* x  = (const float*)d_in[0];
    const float* w1 = (const float*)d_in[1];
    const float* b1 = (const float*)d_in[2];
    const float* w2 = (const float*)d_in[3];
    const float* b2 = (const float*)d_in[4];
    const float* w3 = (const float*)d_in[5];
    const float* b3 = (const float*)d_in[6];
    float* out = (float*)d_out;

    dim3 grid(NGRP, NB, 4);   // (group, batch, pixel-chunk) — chunk slowest
    dim3 block(256);
    hoaf_kernel<<<grid, block, 0, stream>>>(x, w1, b1, w2, b2, w3, b3, out);
}